// Round 11
// baseline (4152.794 us; speedup 1.0000x reference)
//
#include <hip/hip_runtime.h>
#include <hip/hip_bf16.h>

#define B_ 32
#define S_ 64
#define H_ 512
#define V_ 32000
#define T_ 64

typedef __bf16 bf16x8 __attribute__((ext_vector_type(8)));
typedef float f32x4 __attribute__((ext_vector_type(4)));

__device__ __forceinline__ float fast_tanh(float x) {
  float e = __expf(2.0f * x);
  return 1.0f - 2.0f / (e + 1.0f);
}
__device__ __forceinline__ float fast_sigmoid(float x) {
  return 1.0f / (1.0f + __expf(-x));
}
__device__ __forceinline__ int ld_agent(const int* p) {
  return __hip_atomic_load(p, __ATOMIC_RELAXED, __HIP_MEMORY_SCOPE_AGENT);
}
__device__ __forceinline__ void st_agent_f(float* p, float v) {
  __hip_atomic_store(p, v, __ATOMIC_RELAXED, __HIP_MEMORY_SCOPE_AGENT);
}
__device__ __forceinline__ void st_agent_i(int* p, int v) {
  __hip_atomic_store(p, v, __ATOMIC_RELAXED, __HIP_MEMORY_SCOPE_AGENT);
}

// ---------------- prep kernels ----------------

__global__ __launch_bounds__(256) void k_emb_gather(const int* __restrict__ target,
    const float* __restrict__ emb, __hip_bfloat16* __restrict__ emb_bf) {
  int row = blockIdx.x;                 // t*32 + b
  int t = row >> 5, b = row & 31;
  int tok = (t == 0) ? 0 : target[b * T_ + t - 1];
  const float* src = emb + (size_t)tok * H_;
  __hip_bfloat16* dst = emb_bf + (size_t)row * H_;
  for (int jj = threadIdx.x; jj < H_; jj += 256) dst[jj] = __float2bfloat16(src[jj]);
}

__global__ __launch_bounds__(256) void k_cvt_dense(const float* __restrict__ src,
    __hip_bfloat16* __restrict__ dst, int n4) {
  int i = blockIdx.x * 256 + threadIdx.x;
  if (i < n4) {
    const float4 v = ((const float4*)src)[i];
    union { __hip_bfloat16 h[4]; uint2 u; } cv;
    cv.h[0] = __float2bfloat16(v.x); cv.h[1] = __float2bfloat16(v.y);
    cv.h[2] = __float2bfloat16(v.z); cv.h[3] = __float2bfloat16(v.w);
    *(uint2*)(dst + (size_t)i * 4) = cv.u;
  }
}

__global__ __launch_bounds__(128) void k_cvt_wihc(const float* __restrict__ W_ih,
    __hip_bfloat16* __restrict__ dst) {
  const int row = blockIdx.x;           // 0..1535
  const int c4 = threadIdx.x * 4;
  const float4 v = *(const float4*)(W_ih + (size_t)row * 1024 + 512 + c4);
  union { __hip_bfloat16 h[4]; uint2 u; } cv;
  cv.h[0] = __float2bfloat16(v.x); cv.h[1] = __float2bfloat16(v.y);
  cv.h[2] = __float2bfloat16(v.z); cv.h[3] = __float2bfloat16(v.w);
  *(uint2*)(dst + (size_t)row * 512 + c4) = cv.u;
}

__global__ __launch_bounds__(256) void k_cvt_wqh(const float* __restrict__ Wq,
    const float* __restrict__ W_hh, __hip_bfloat16* __restrict__ wq_bf,
    __hip_bfloat16* __restrict__ whh_bf) {
  const int row = blockIdx.x;           // 0..2047
  const int c2 = threadIdx.x * 2;
  const float* src = (row < 512) ? (Wq + (size_t)row * 512)
                                 : (W_hh + (size_t)(row - 512) * 512);
  __hip_bfloat16* dst = (row < 512) ? (wq_bf + (size_t)row * 512)
                                    : (whh_bf + (size_t)(row - 512) * 512);
  const float2 v = *(const float2*)(src + c2);
  union { __hip_bfloat16 h[2]; unsigned u; } cv;
  cv.h[0] = __float2bfloat16(v.x); cv.h[1] = __float2bfloat16(v.y);
  *(unsigned*)(dst + c2) = cv.u;
}

__global__ __launch_bounds__(256) void k_init(const float* __restrict__ ehs,
    float* __restrict__ h_st0, int* __restrict__ flags, float* __restrict__ rowsum) {
  int i = blockIdx.x * 256 + threadIdx.x;     // grid 64*256 = 16384
  if (i < B_ * H_) h_st0[i] = ehs[i];
  if (i < 512)
    __hip_atomic_store(&flags[i], 0, __ATOMIC_RELAXED, __HIP_MEMORY_SCOPE_AGENT);
  if (i < B_ * T_) rowsum[i] = 0.f;
}

// ---------------- generic bf16-MFMA GEMM: C[M,N] = A[M,K] @ B[N,K]^T (+bias) ----------------

__global__ __launch_bounds__(256) void k_gemm_bf16(
    const __hip_bfloat16* __restrict__ A, int lda,
    const float* __restrict__ B, int ldb,
    const float* __restrict__ bias,
    float* __restrict__ C, int ldc, int K) {
  __shared__ float pool[128 * 68];
  __hip_bfloat16* Asub = (__hip_bfloat16*)pool;
  __hip_bfloat16* Bsub = (__hip_bfloat16*)(pool + 2048);
  const int tid = threadIdx.x;
  const int lane = tid & 63, wave = tid >> 6;
  const int wr = wave >> 1, wc = wave & 1;
  const int n0 = blockIdx.x * 128, m0 = blockIdx.y * 128;
  f32x4 acc[4][4];
#pragma unroll
  for (int i = 0; i < 4; ++i)
#pragma unroll
    for (int jj = 0; jj < 4; ++jj) acc[i][jj] = (f32x4){0.f, 0.f, 0.f, 0.f};

  for (int k0 = 0; k0 < K; k0 += 32) {
    uint4 a_v[2];
#pragma unroll
    for (int rr = 0; rr < 2; ++rr) {
      const int seg = tid + rr * 256;
      const int row = seg >> 2, ks8 = (seg & 3) * 8;
      a_v[rr] = *(const uint4*)(A + (size_t)(m0 + row) * lda + k0 + ks8);
    }
    float4 b_v[4];
#pragma unroll
    for (int rr = 0; rr < 4; ++rr) {
      const int idx = tid + rr * 256;
      const int n = idx >> 3, kg = (idx & 7) * 4;
      b_v[rr] = *(const float4*)(B + (size_t)(n0 + n) * ldb + k0 + kg);
    }
    __syncthreads();
#pragma unroll
    for (int rr = 0; rr < 2; ++rr) {
      const int seg = tid + rr * 256;
      *(uint4*)(Asub + seg * 8) = a_v[rr];
    }
#pragma unroll
    for (int rr = 0; rr < 4; ++rr) {
      const int idx = tid + rr * 256;
      const int n = idx >> 3, kg = (idx & 7) * 4;
      union { __hip_bfloat16 h[4]; uint2 u; } cv;
      cv.h[0] = __float2bfloat16(b_v[rr].x);
      cv.h[1] = __float2bfloat16(b_v[rr].y);
      cv.h[2] = __float2bfloat16(b_v[rr].z);
      cv.h[3] = __float2bfloat16(b_v[rr].w);
      *(uint2*)(Bsub + n * 32 + kg) = cv.u;
    }
    __syncthreads();
    bf16x8 af[4], bfr[4];
#pragma unroll
    for (int mi = 0; mi < 4; ++mi)
      af[mi] = *(const bf16x8*)(Asub + (wr * 64 + mi * 16 + (lane & 15)) * 32 + (lane >> 4) * 8);
#pragma unroll
    for (int ni = 0; ni < 4; ++ni)
      bfr[ni] = *(const bf16x8*)(Bsub + (wc * 64 + ni * 16 + (lane & 15)) * 32 + (lane >> 4) * 8);
#pragma unroll
    for (int mi = 0; mi < 4; ++mi)
#pragma unroll
      for (int ni = 0; ni < 4; ++ni)
        acc[mi][ni] = __builtin_amdgcn_mfma_f32_16x16x32_bf16(af[mi], bfr[ni], acc[mi][ni], 0, 0, 0);
  }

  float* Cs = pool;
  const int r4 = (lane >> 4) * 4, cc = lane & 15;
#pragma unroll
  for (int hf = 0; hf < 2; ++hf) {
    __syncthreads();
    if (wc == hf) {
#pragma unroll
      for (int ni = 0; ni < 4; ++ni) {
        const float bb = bias ? bias[n0 + hf * 64 + ni * 16 + cc] : 0.f;
#pragma unroll
        for (int mi = 0; mi < 4; ++mi)
#pragma unroll
          for (int i = 0; i < 4; ++i)
            Cs[(wr * 64 + mi * 16 + r4 + i) * 68 + ni * 16 + cc] = acc[mi][ni][i] + bb;
      }
    }
    __syncthreads();
    const int rowp = tid >> 4, colg = tid & 15;
#pragma unroll
    for (int pass = 0; pass < 8; ++pass) {
      const int row = pass * 16 + rowp;
      const float4 v = *(const float4*)(Cs + row * 68 + colg * 4);
      *(float4*)(C + (size_t)(m0 + row) * ldc + n0 + hf * 64 + colg * 4) = v;
    }
  }
}

// ---------------- recurrence: 16 clusters x 8 blocks, 2 batches each, ONE exchange/step ----------------
// block = c*8 + j; batches b0=2c, b1=2c+1 alternate so the h-exchange of one
// hides under the other's compute. Each block computes the FULL q (so scores/
// softmax are local) and only slice j of gh/gic/gates. Handoff protocol is
// r7-proven: agent write-through stores + vmcnt(0) + monotone 1-line flags.

__global__ __launch_bounds__(256) void k_recur(
    const __hip_bfloat16* __restrict__ wq_bf, const __hip_bfloat16* __restrict__ whh_bf,
    const float* __restrict__ bq,
    const __hip_bfloat16* __restrict__ kproj_bf,
    const float* __restrict__ Wv, const float* __restrict__ bv,
    const __hip_bfloat16* __restrict__ encT_bf, const float* __restrict__ giemb,
    const float* __restrict__ b_hh,
    float* h_st, int* h_flags,
    float* __restrict__ attn_out, __hip_bfloat16* __restrict__ Hall,
    float* __restrict__ hfin) {
  const int tid = threadIdx.x;
  const int c = blockIdx.x >> 3, j = blockIdx.x & 7;
  const int b0 = c * 2, b1 = c * 2 + 1;
  const int rowg = tid >> 3, lane8 = tid & 7;
  const int s_idx = tid >> 2, q4 = tid & 3;

  __shared__ float h_s[8 * 68];
  __shared__ float wv_s[512];
  __shared__ float bq_s[512];
  __shared__ float q_s[512];
  __shared__ float red[64];
  __shared__ float w_s[64];
  __shared__ float gic_s[192];
  __shared__ float gh_s[192];

  if (tid < 128) {
    *(float4*)(wv_s + tid * 4) = *(const float4*)(Wv + tid * 4);
    *(float4*)(bq_s + tid * 4) = *(const float4*)(bq + tid * 4);
  }
  const float bv0 = bv[0];
  __syncthreads();

  auto do_batch = [&](int b, int t) {
    // ---- wait h_st[t][b] published by all 8 slices (1-line poll) ----
    if (tid < 8) {
      while (ld_agent(&h_flags[b * 16 + tid]) < t) __builtin_amdgcn_s_sleep(1);
    }
    __syncthreads();
    asm volatile("" ::: "memory");

    const float* h_t = h_st + (size_t)t * (B_ * H_) + b * H_;
    if (tid < 128) {
      const float4 v = *(const float4*)(h_t + tid * 4);
      const int g = (tid * 4) >> 6, off = (tid * 4) & 63;
      *(float4*)(h_s + g * 68 + off) = v;
    }
    __syncthreads();

    f32x4 hf4[16];
#pragma unroll
    for (int i = 0; i < 16; ++i)
      hf4[i] = *(const f32x4*)(h_s + lane8 * 68 + i * 4);

    // streaming bf16 GEMV: dot(wrow[lane8*64 .. +64), h-chunk), reduce over lane8
    auto dotw = [&](const __hip_bfloat16* wrow) -> float {
      const uint4* w8 = (const uint4*)wrow;
      float p = 0.f;
#pragma unroll
      for (int i = 0; i < 8; ++i) {
        const uint4 w = w8[lane8 * 8 + i];
        const f32x4 ha = hf4[2 * i], hb = hf4[2 * i + 1];
        p += __uint_as_float(w.x << 16) * ha[0] + __uint_as_float(w.x & 0xffff0000u) * ha[1];
        p += __uint_as_float(w.y << 16) * ha[2] + __uint_as_float(w.y & 0xffff0000u) * ha[3];
        p += __uint_as_float(w.z << 16) * hb[0] + __uint_as_float(w.z & 0xffff0000u) * hb[1];
        p += __uint_as_float(w.w << 16) * hb[2] + __uint_as_float(w.w & 0xffff0000u) * hb[3];
      }
      p += __shfl_xor(p, 1); p += __shfl_xor(p, 2); p += __shfl_xor(p, 4);
      return p;
    };

    // ---- FULL q: 16 rows per rowg-group (covers all 512 rows) ----
#pragma unroll 2
    for (int rr = 0; rr < 16; ++rr) {
      const int row = rr * 32 + rowg;
      const float p = dotw(wq_bf + (size_t)row * 512);
      if (lane8 == 0) q_s[row] = p + bq_s[row];
    }
    // ---- gh slice j (192 rows) ----
#pragma unroll
    for (int i = 0; i < 6; ++i) {
      const int row = (i >> 1) * 512 + j * 64 + (i & 1) * 32 + rowg;
      const float p = dotw(whh_bf + (size_t)row * 512);
      if (lane8 == 0) gh_s[i * 32 + rowg] = p;
    }
    __syncthreads();

    // ---- FULL scores: thread (s, q4) covers 128 dims, bf16 kproj ----
    {
      const uint4* kp = (const uint4*)(kproj_bf + ((size_t)(b * S_ + s_idx)) * H_ + q4 * 128);
      const float4* qp = (const float4*)(q_s + q4 * 128);
      const float4* wp = (const float4*)(wv_s + q4 * 128);
      float sc = 0.f;
#pragma unroll
      for (int i = 0; i < 16; ++i) {
        const uint4 k = kp[i];
        const float4 qa = qp[2 * i], qb = qp[2 * i + 1];
        const float4 wa = wp[2 * i], wb = wp[2 * i + 1];
        sc += wa.x * fast_tanh(qa.x + __uint_as_float(k.x << 16));
        sc += wa.y * fast_tanh(qa.y + __uint_as_float(k.x & 0xffff0000u));
        sc += wa.z * fast_tanh(qa.z + __uint_as_float(k.y << 16));
        sc += wa.w * fast_tanh(qa.w + __uint_as_float(k.y & 0xffff0000u));
        sc += wb.x * fast_tanh(qb.x + __uint_as_float(k.z << 16));
        sc += wb.y * fast_tanh(qb.y + __uint_as_float(k.z & 0xffff0000u));
        sc += wb.z * fast_tanh(qb.z + __uint_as_float(k.w << 16));
        sc += wb.w * fast_tanh(qb.w + __uint_as_float(k.w & 0xffff0000u));
      }
      sc += __shfl_xor(sc, 1); sc += __shfl_xor(sc, 2);
      if (q4 == 0) red[s_idx] = sc;
    }
    __syncthreads();

    // ---- softmax (local; identical math to r7) ----
    if (tid < 64) {
      float sc = red[tid] + bv0;
      float m = sc;
#pragma unroll
      for (int d = 32; d > 0; d >>= 1) m = fmaxf(m, __shfl_xor(m, d));
      const float e = __expf(sc - m);
      float sum = e;
#pragma unroll
      for (int d = 32; d > 0; d >>= 1) sum += __shfl_xor(sum, d);
      const float w = e / sum;
      w_s[tid] = w;
      if (j == (b & 7)) attn_out[((size_t)b * T_ + t) * S_ + tid] = w;
    }
    __syncthreads();

    // ---- gic slice j (bf16 encT) ----
    if (tid < 192) {
      const int g = tid >> 6, dd = tid & 63;
      const int grow = g * H_ + j * 64 + dd;
      const uint4* ep = (const uint4*)(encT_bf + (size_t)grow * 2048 + b * 64);
      const float4* wp4 = (const float4*)w_s;
      float a = 0.f;
#pragma unroll
      for (int i = 0; i < 8; ++i) {
        const uint4 e4 = ep[i];
        const float4 w0 = wp4[2 * i], w1 = wp4[2 * i + 1];
        a += __uint_as_float(e4.x << 16) * w0.x + __uint_as_float(e4.x & 0xffff0000u) * w0.y;
        a += __uint_as_float(e4.y << 16) * w0.z + __uint_as_float(e4.y & 0xffff0000u) * w0.w;
        a += __uint_as_float(e4.z << 16) * w1.x + __uint_as_float(e4.z & 0xffff0000u) * w1.y;
        a += __uint_as_float(e4.w << 16) * w1.z + __uint_as_float(e4.w & 0xffff0000u) * w1.w;
      }
      gic_s[tid] = a;
    }
    __syncthreads();

    // ---- gates for h-dims [j*64,(j+1)*64) ----
    if (tid < 64) {
      const int hh = j * 64 + tid;
      const size_t grow = ((size_t)t * B_ + b) * 1536;
      const float ir  = giemb[grow + hh]        + gic_s[tid];
      const float iz  = giemb[grow + 512 + hh]  + gic_s[64 + tid];
      const float in_ = giemb[grow + 1024 + hh] + gic_s[128 + tid];
      const float hr  = gh_s[tid]        + b_hh[hh];
      const float hz  = gh_s[64 + tid]   + b_hh[512 + hh];
      const float hn  = gh_s[128 + tid]  + b_hh[1024 + hh];
      const float rg = fast_sigmoid(ir + hr);
      const float zg = fast_sigmoid(iz + hz);
      const float ng = fast_tanh(in_ + rg * hn);
      const float ho = h_s[j * 68 + tid];
      const float hv = (1.f - zg) * ng + zg * ho;
      st_agent_f(&h_st[(size_t)(t + 1) * (B_ * H_) + b * H_ + hh], hv);
      Hall[((size_t)b * T_ + t) * H_ + hh] = __float2bfloat16(hv);
      if (t == T_ - 1) hfin[b * H_ + hh] = hv;
    }
    asm volatile("s_waitcnt vmcnt(0)" ::: "memory");
    __syncthreads();
    if (tid == 0)
      st_agent_i(&h_flags[b * 16 + j], t + 1);
  };

  for (int t = 0; t < T_; ++t) {
    do_batch(b0, t);
    do_batch(b1, t);
  }
}

// ---------------- logits GEMM + fused sumexp (XCD-chunked n-tiles) ----------------
// |h|<=1 by GRU construction -> |logit| <~ 10 -> no-max sumexp is fp32-safe.

__global__ __launch_bounds__(256) void k_logits(
    const __hip_bfloat16* __restrict__ Hall, const float* __restrict__ Wo,
    const float* __restrict__ bo, float* __restrict__ out0,
    float* __restrict__ rowsum) {
  __shared__ float pool[128 * 68];
  __hip_bfloat16* Asub = (__hip_bfloat16*)pool;
  __hip_bfloat16* Bsub = (__hip_bfloat16*)(pool + 2048);
  const int tid = threadIdx.x;
  const int lane = tid & 63, wave = tid >> 6;
  const int wr = wave >> 1, wc = wave & 1;
  const int flat = blockIdx.x;                  // 0..3999
  const int nf = (flat & 7) * 500 + (flat >> 3);
  const int m0 = (nf & 15) * 128, n0 = (nf >> 4) * 128;
  f32x4 acc[4][4];
#pragma unroll
  for (int i = 0; i < 4; ++i)
#pragma unroll
    for (int jj = 0; jj < 4; ++jj) acc[i][jj] = (f32x4){0.f, 0.f, 0.f, 0.f};

  for (int k0 = 0; k0 < 512; k0 += 32) {
    uint4 a_v[2];
#pragma unroll
    for (int rr = 0; rr < 2; ++rr) {
      const int seg = tid + rr * 256;
      const int row = seg >> 2, ks8 = (seg & 3) * 8;
      a_v[rr] = *(const uint4*)(Hall + (size_t)(m0 + row) * 512 + k0 + ks8);
    }
    float4 b_v[4];
#pragma unroll
    for (int rr = 0; rr < 4; ++rr) {
      const int idx = tid + rr * 256;
      const int n = idx >> 3, kg = (idx & 7) * 4;
      b_v[rr] = *(const float4*)(Wo + (size_t)(n0 + n) * 512 + k0 + kg);
    }
    __syncthreads();
#pragma unroll
    for (int rr = 0; rr < 2; ++rr) {
      const int seg = tid + rr * 256;
      *(uint4*)(Asub + seg * 8) = a_v[rr];
    }
#pragma unroll
    for (int rr = 0; rr < 4; ++rr) {
      const int idx = tid + rr * 256;
      const int n = idx >> 3, kg = (idx & 7) * 4;
      union { __hip_bfloat16 h[4]; uint2 u; } cv;
      cv.h[0] = __float2bfloat16(b_v[rr].x);
      cv.h[1] = __float2bfloat16(b_v[rr].y);
      cv.h[2] = __float2bfloat16(b_v[rr].z);
      cv.h[3] = __float2bfloat16(b_v[rr].w);
      *(uint2*)(Bsub + n * 32 + kg) = cv.u;
    }
    __syncthreads();
    bf16x8 af[4], bfr[4];
#pragma unroll
    for (int mi = 0; mi < 4; ++mi)
      af[mi] = *(const bf16x8*)(Asub + (wr * 64 + mi * 16 + (lane & 15)) * 32 + (lane >> 4) * 8);
#pragma unroll
    for (int ni = 0; ni < 4; ++ni)
      bfr[ni] = *(const bf16x8*)(Bsub + (wc * 64 + ni * 16 + (lane & 15)) * 32 + (lane >> 4) * 8);
#pragma unroll
    for (int mi = 0; mi < 4; ++mi)
#pragma unroll
      for (int ni = 0; ni < 4; ++ni)
        acc[mi][ni] = __builtin_amdgcn_mfma_f32_16x16x32_bf16(af[mi], bfr[ni], acc[mi][ni], 0, 0, 0);
  }

  float* Cs = pool;
  const int r4 = (lane >> 4) * 4, cc = lane & 15;
#pragma unroll
  for (int hf = 0; hf < 2; ++hf) {
    __syncthreads();
    if (wc == hf) {
#pragma unroll
      for (int ni = 0; ni < 4; ++ni) {
        const float bias = bo[n0 + hf * 64 + ni * 16 + cc];
#pragma unroll
        for (int mi = 0; mi < 4; ++mi)
#pragma unroll
          for (int i = 0; i < 4; ++i)
            Cs[(wr * 64 + mi * 16 + r4 + i) * 68 + ni * 16 + cc] = acc[mi][ni][i] + bias;
      }
    }
    __syncthreads();
    const int rowp = tid >> 4, colg = tid & 15;
#pragma unroll
    for (int pass = 0; pass < 8; ++pass) {
      const int row = pass * 16 + rowp;
      const float4 v = *(const float4*)(Cs + row * 68 + colg * 4);
      *(float4*)(out0 + (size_t)(m0 + row) * V_ + n0 + hf * 64 + colg * 4) = v;
      float e = __expf(v.x) + __expf(v.y) + __expf(v.z) + __expf(v.w);
#pragma unroll
      for (int d = 1; d < 16; d <<= 1) e += __shfl_xor(e, d);
      if (colg == 0) atomicAdd(&rowsum[m0 + row], e);
    }
  }
}

// ---------------- log_softmax apply: out -= log(rowsum[row]) ----------------

__global__ __launch_bounds__(256) void k_lsm_apply(float* __restrict__ out0,
    const float* __restrict__ rowsum) {
  const int row = blockIdx.x, tid = threadIdx.x;
  const float lse = __logf(rowsum[row]);
  float4* p = (float4*)(out0 + (size_t)row * V_);
  for (int i = tid; i < V_ / 4; i += 256) {
    float4 v = p[i];
    v.x -= lse; v.y -= lse; v.z -= lse; v.w -= lse;
    p[i] = v;
  }
}

// ---------------- host ----------------

extern "C" void kernel_launch(void* const* d_in, const int* in_sizes, int n_in,
                              void* d_out, int out_size, void* d_ws, size_t ws_size,
                              hipStream_t stream) {
  (void)in_sizes; (void)n_in; (void)out_size; (void)ws_size;
  const float* enc  = (const float*)d_in[0];
  const float* ehs  = (const float*)d_in[1];
  const int*   tgt  = (const int*)d_in[2];
  const float* emb  = (const float*)d_in[3];
  const float* Wq   = (const float*)d_in[4];
  const float* bq   = (const float*)d_in[5];
  const float* Wk   = (const float*)d_in[6];
  const float* bk   = (const float*)d_in[7];
  const float* Wv   = (const float*)d_in[8];
  const float* bv   = (const float*)d_in[9];
  const float* W_ih = (const float*)d_in[10];
  const float* W_hh = (const float*)d_in[11];
  const float* b_ih = (const float*)d_in[12];
  const float* b_hh = (const float*)d_in[13];
  const float* Wo   = (const float*)d_in[14];
  const float* bo   = (const float*)d_in[15];

  float* out0 = (float*)d_out;                          // log_probs [2048, V]
  float* out1 = out0 + (size_t)B_ * T_ * V_;            // h_final [B*H]
  float* out2 = out1 + (size_t)B_ * H_;                 // attentions [B*T, S]

  // out0 doubles as scratch; k_logits overwrites all of it afterwards.
  float* kproj    = out0;                 // [0, 1,048,576)
  float* giemb    = out0 + 1048576;       // [.., 4,194,304)
  float* encprojT = out0 + 4194304;       // [1536][2048] -> [.., 7,340,032)
  float* h_st     = out0 + 7340032;       // 65 x 16384 -> [.., 8,404,992)
  __hip_bfloat16* enc_bf   = (__hip_bfloat16*)(out0 + 8404992);   // 1M bf16
  __hip_bfloat16* emb_bf   = (__hip_bfloat16*)(out0 + 8929280);   // 1M bf16
  __hip_bfloat16* wihc_bf  = (__hip_bfloat16*)(out0 + 9453568);   // 0.75M bf16
  __hip_bfloat16* wq_bf    = (__hip_bfloat16*)(out0 + 9846784);   // 256K bf16
  __hip_bfloat16* whh_bf   = (__hip_bfloat16*)(out0 + 9977856);   // 0.75M bf16
  __hip_bfloat16* kproj_bf = (__hip_bfloat16*)(out0 + 10371072);  // 1M bf16
  __hip_bfloat16* encT_bf  = (__hip_bfloat16*)(out0 + 10895360);  // 3M bf16

  __hip_bfloat16* Hall = (__hip_bfloat16*)d_ws;                    // 2 MB
  int* flags = (int*)((char*)d_ws + (size_t)2 * 1024 * 1024);      // 512 ints
  float* rowsum = (float*)((char*)d_ws + (size_t)2 * 1024 * 1024 + 2048);  // 2048 f

  k_emb_gather<<<2048, 256, 0, stream>>>(tgt, emb, emb_bf);
  k_cvt_dense<<<1024, 256, 0, stream>>>(enc, enc_bf, 262144);
  k_cvt_wihc<<<1536, 128, 0, stream>>>(W_ih, wihc_bf);
  k_cvt_wqh<<<2048, 256, 0, stream>>>(Wq, W_hh, wq_bf, whh_bf);
  k_init<<<64, 256, 0, stream>>>(ehs, h_st, flags, rowsum);

  // kproj[2048,512] = enc @ Wk^T + bk
  k_gemm_bf16<<<dim3(4, 16), 256, 0, stream>>>(enc_bf, 512, Wk, 512, bk, kproj, 512, 512);
  // giemb[2048,1536] = emb_all @ W_ih[:, :512]^T + b_ih
  k_gemm_bf16<<<dim3(12, 16), 256, 0, stream>>>(emb_bf, 512, W_ih, 1024, b_ih, giemb, 1536, 512);
  // encprojT[1536,2048] = W_ihc @ enc^T
  k_gemm_bf16<<<dim3(16, 12), 256, 0, stream>>>(wihc_bf, 512, enc, 512, nullptr, encprojT, 2048, 512);

  // bf16 copies for the recurrence's streamed operands
  k_cvt_dense<<<1024, 256, 0, stream>>>(kproj, kproj_bf, 262144);
  k_cvt_dense<<<3072, 256, 0, stream>>>(encprojT, encT_bf, 786432);

  k_recur<<<128, 256, 0, stream>>>(wq_bf, whh_bf, bq, kproj_bf, Wv, bv, encT_bf,
                                   giemb, b_hh, h_st, flags, out2, Hall, out1);

  k_logits<<<4000, 256, 0, stream>>>(Hall, Wo, bo, out0, rowsum);
  k_lsm_apply<<<(B_ * T_), 256, 0, stream>>>(out0, rowsum);
}

// Round 12
// 1253.506 us; speedup vs baseline: 3.3129x; 3.3129x over previous
//
#include <hip/hip_runtime.h>
#include <hip/hip_bf16.h>

#define B_ 32
#define S_ 64
#define H_ 512
#define V_ 32000
#define T_ 64

typedef __bf16 bf16x8 __attribute__((ext_vector_type(8)));
typedef float f32x4 __attribute__((ext_vector_type(4)));

__device__ __forceinline__ float fast_tanh(float x) {
  float e = __expf(2.0f * x);
  return 1.0f - 2.0f / (e + 1.0f);
}
__device__ __forceinline__ float fast_sigmoid(float x) {
  return 1.0f / (1.0f + __expf(-x));
}
__device__ __forceinline__ int ld_agent(const int* p) {
  return __hip_atomic_load(p, __ATOMIC_RELAXED, __HIP_MEMORY_SCOPE_AGENT);
}
__device__ __forceinline__ void st_agent_f(float* p, float v) {
  __hip_atomic_store(p, v, __ATOMIC_RELAXED, __HIP_MEMORY_SCOPE_AGENT);
}
__device__ __forceinline__ void st_agent_i(int* p, int v) {
  __hip_atomic_store(p, v, __ATOMIC_RELAXED, __HIP_MEMORY_SCOPE_AGENT);
}

// ---------------- prep kernels ----------------

__global__ __launch_bounds__(256) void k_emb_gather(const int* __restrict__ target,
    const float* __restrict__ emb, __hip_bfloat16* __restrict__ emb_bf) {
  int row = blockIdx.x;                 // t*32 + b
  int t = row >> 5, b = row & 31;
  int tok = (t == 0) ? 0 : target[b * T_ + t - 1];
  const float* src = emb + (size_t)tok * H_;
  __hip_bfloat16* dst = emb_bf + (size_t)row * H_;
  for (int jj = threadIdx.x; jj < H_; jj += 256) dst[jj] = __float2bfloat16(src[jj]);
}

__global__ __launch_bounds__(256) void k_cvt_dense(const float* __restrict__ src,
    __hip_bfloat16* __restrict__ dst, int n4) {
  int i = blockIdx.x * 256 + threadIdx.x;
  if (i < n4) {
    const float4 v = ((const float4*)src)[i];
    union { __hip_bfloat16 h[4]; uint2 u; } cv;
    cv.h[0] = __float2bfloat16(v.x); cv.h[1] = __float2bfloat16(v.y);
    cv.h[2] = __float2bfloat16(v.z); cv.h[3] = __float2bfloat16(v.w);
    *(uint2*)(dst + (size_t)i * 4) = cv.u;
  }
}

__global__ __launch_bounds__(128) void k_cvt_wihc(const float* __restrict__ W_ih,
    __hip_bfloat16* __restrict__ dst) {
  const int row = blockIdx.x;           // 0..1535
  const int c4 = threadIdx.x * 4;
  const float4 v = *(const float4*)(W_ih + (size_t)row * 1024 + 512 + c4);
  union { __hip_bfloat16 h[4]; uint2 u; } cv;
  cv.h[0] = __float2bfloat16(v.x); cv.h[1] = __float2bfloat16(v.y);
  cv.h[2] = __float2bfloat16(v.z); cv.h[3] = __float2bfloat16(v.w);
  *(uint2*)(dst + (size_t)row * 512 + c4) = cv.u;
}

__global__ __launch_bounds__(256) void k_cvt_wqh(const float* __restrict__ Wq,
    const float* __restrict__ W_hh, __hip_bfloat16* __restrict__ wq_bf,
    __hip_bfloat16* __restrict__ whh_bf) {
  const int row = blockIdx.x;           // 0..2047
  const int c2 = threadIdx.x * 2;
  const float* src = (row < 512) ? (Wq + (size_t)row * 512)
                                 : (W_hh + (size_t)(row - 512) * 512);
  __hip_bfloat16* dst = (row < 512) ? (wq_bf + (size_t)row * 512)
                                    : (whh_bf + (size_t)(row - 512) * 512);
  const float2 v = *(const float2*)(src + c2);
  union { __hip_bfloat16 h[2]; unsigned u; } cv;
  cv.h[0] = __float2bfloat16(v.x); cv.h[1] = __float2bfloat16(v.y);
  *(unsigned*)(dst + c2) = cv.u;
}

__global__ __launch_bounds__(256) void k_init(const float* __restrict__ ehs,
    float* __restrict__ h_st0, int* __restrict__ flags, float* __restrict__ rowsum) {
  int i = blockIdx.x * 256 + threadIdx.x;     // grid 64*256 = 16384
  if (i < B_ * H_) h_st0[i] = ehs[i];
  if (i < 1024)
    __hip_atomic_store(&flags[i], 0, __ATOMIC_RELAXED, __HIP_MEMORY_SCOPE_AGENT);
  if (i < B_ * T_) rowsum[i] = 0.f;
}

// ---------------- generic bf16-MFMA GEMM: C[M,N] = A[M,K] @ B[N,K]^T (+bias) ----------------

__global__ __launch_bounds__(256) void k_gemm_bf16(
    const __hip_bfloat16* __restrict__ A, int lda,
    const float* __restrict__ B, int ldb,
    const float* __restrict__ bias,
    float* __restrict__ C, int ldc, int K) {
  __shared__ float pool[128 * 68];
  __hip_bfloat16* Asub = (__hip_bfloat16*)pool;
  __hip_bfloat16* Bsub = (__hip_bfloat16*)(pool + 2048);
  const int tid = threadIdx.x;
  const int lane = tid & 63, wave = tid >> 6;
  const int wr = wave >> 1, wc = wave & 1;
  const int n0 = blockIdx.x * 128, m0 = blockIdx.y * 128;
  f32x4 acc[4][4];
#pragma unroll
  for (int i = 0; i < 4; ++i)
#pragma unroll
    for (int jj = 0; jj < 4; ++jj) acc[i][jj] = (f32x4){0.f, 0.f, 0.f, 0.f};

  for (int k0 = 0; k0 < K; k0 += 32) {
    uint4 a_v[2];
#pragma unroll
    for (int rr = 0; rr < 2; ++rr) {
      const int seg = tid + rr * 256;
      const int row = seg >> 2, ks8 = (seg & 3) * 8;
      a_v[rr] = *(const uint4*)(A + (size_t)(m0 + row) * lda + k0 + ks8);
    }
    float4 b_v[4];
#pragma unroll
    for (int rr = 0; rr < 4; ++rr) {
      const int idx = tid + rr * 256;
      const int n = idx >> 3, kg = (idx & 7) * 4;
      b_v[rr] = *(const float4*)(B + (size_t)(n0 + n) * ldb + k0 + kg);
    }
    __syncthreads();
#pragma unroll
    for (int rr = 0; rr < 2; ++rr) {
      const int seg = tid + rr * 256;
      *(uint4*)(Asub + seg * 8) = a_v[rr];
    }
#pragma unroll
    for (int rr = 0; rr < 4; ++rr) {
      const int idx = tid + rr * 256;
      const int n = idx >> 3, kg = (idx & 7) * 4;
      union { __hip_bfloat16 h[4]; uint2 u; } cv;
      cv.h[0] = __float2bfloat16(b_v[rr].x);
      cv.h[1] = __float2bfloat16(b_v[rr].y);
      cv.h[2] = __float2bfloat16(b_v[rr].z);
      cv.h[3] = __float2bfloat16(b_v[rr].w);
      *(uint2*)(Bsub + n * 32 + kg) = cv.u;
    }
    __syncthreads();
    bf16x8 af[4], bfr[4];
#pragma unroll
    for (int mi = 0; mi < 4; ++mi)
      af[mi] = *(const bf16x8*)(Asub + (wr * 64 + mi * 16 + (lane & 15)) * 32 + (lane >> 4) * 8);
#pragma unroll
    for (int ni = 0; ni < 4; ++ni)
      bfr[ni] = *(const bf16x8*)(Bsub + (wc * 64 + ni * 16 + (lane & 15)) * 32 + (lane >> 4) * 8);
#pragma unroll
    for (int mi = 0; mi < 4; ++mi)
#pragma unroll
      for (int ni = 0; ni < 4; ++ni)
        acc[mi][ni] = __builtin_amdgcn_mfma_f32_16x16x32_bf16(af[mi], bfr[ni], acc[mi][ni], 0, 0, 0);
  }

  float* Cs = pool;
  const int r4 = (lane >> 4) * 4, cc = lane & 15;
#pragma unroll
  for (int hf = 0; hf < 2; ++hf) {
    __syncthreads();
    if (wc == hf) {
#pragma unroll
      for (int ni = 0; ni < 4; ++ni) {
        const float bb = bias ? bias[n0 + hf * 64 + ni * 16 + cc] : 0.f;
#pragma unroll
        for (int mi = 0; mi < 4; ++mi)
#pragma unroll
          for (int i = 0; i < 4; ++i)
            Cs[(wr * 64 + mi * 16 + r4 + i) * 68 + ni * 16 + cc] = acc[mi][ni][i] + bb;
      }
    }
    __syncthreads();
    const int rowp = tid >> 4, colg = tid & 15;
#pragma unroll
    for (int pass = 0; pass < 8; ++pass) {
      const int row = pass * 16 + rowp;
      const float4 v = *(const float4*)(Cs + row * 68 + colg * 4);
      *(float4*)(C + (size_t)(m0 + row) * ldc + n0 + hf * 64 + colg * 4) = v;
    }
  }
}

// ---------------- recurrence: 32 clusters x 8 blocks, SAME-XCD clusters ----------------
// r7 structure + r7 protocol VERBATIM (agent-scope write-through payloads +
// vmcnt(0) + monotone 1-line flags) — only the cluster->bid mapping changes:
// bid = (b>>2) + 8*(b&3) + 32*j  =>  all 8 members of cluster b share bid%8
// (= same XCD under round-robin dispatch), so flag/payload hops resolve at the
// local L2 instead of crossing the LLC. Correct under ANY placement.

__global__ __launch_bounds__(256) void k_recur(
    const __hip_bfloat16* __restrict__ wq_bf, const __hip_bfloat16* __restrict__ whh_bf,
    const float* __restrict__ bq,
    const __hip_bfloat16* __restrict__ kproj_bf,
    const float* __restrict__ Wv, const float* __restrict__ bv,
    const __hip_bfloat16* __restrict__ encT_bf, const float* __restrict__ giemb,
    const float* __restrict__ b_hh,
    float* h_st, float* partial_st, int* flags,
    float* __restrict__ attn_out, __hip_bfloat16* __restrict__ Hall,
    float* __restrict__ hfin) {
  const int tid = threadIdx.x;
  const int bid = blockIdx.x;
  const int b = 4 * (bid & 7) + ((bid >> 3) & 3);   // cluster (batch)
  const int j = bid >> 5;                           // slice
  int* h_flags  = flags;                // [b*16 + j], one line per batch
  int* st_flags = flags + 512;          // [b*16 + j]

  const int rowg = tid >> 3, lane8 = tid & 7;
  const int s_idx = tid >> 2, q4 = tid & 3;
  f32x4 wvr[4];
#pragma unroll
  for (int i = 0; i < 4; ++i)
    wvr[i] = *(const f32x4*)(Wv + j * 64 + q4 * 16 + i * 4);
  float bq2[2];
#pragma unroll
  for (int i = 0; i < 2; ++i) bq2[i] = bq[j * 64 + i * 32 + rowg];
  const float bv0 = bv[0];

  __shared__ float h_s[8 * 68];
  __shared__ float q_s[64];
  __shared__ float gh_s[192];
  __shared__ float ps_s[512];
  __shared__ float w_s[64];
  __shared__ float gic_s[192];

  for (int t = 0; t < T_; ++t) {
    // ---- wait h_st[t][b] published by all 8 slices (1-line poll) ----
    if (tid < 8) {
      while (ld_agent(&h_flags[b * 16 + tid]) < t) __builtin_amdgcn_s_sleep(1);
    }
    __syncthreads();
    asm volatile("" ::: "memory");

    // ---- read h -> padded LDS ----
    const float* h_t = h_st + (size_t)t * (B_ * H_) + b * H_;
    if (tid < 128) {
      const float4 v = *(const float4*)(h_t + tid * 4);
      const int g = (tid * 4) >> 6, off = (tid * 4) & 63;
      *(float4*)(h_s + g * 68 + off) = v;
    }
    __syncthreads();

    f32x4 hf4[16];
#pragma unroll
    for (int i = 0; i < 16; ++i)
      hf4[i] = *(const f32x4*)(h_s + lane8 * 68 + i * 4);

    // streaming bf16 GEMV: dot(wrow[lane8*64 .. +64), h-chunk), reduce over lane8
    auto dotw = [&](const __hip_bfloat16* wrow) -> float {
      const uint4* w8 = (const uint4*)wrow;
      float p = 0.f;
#pragma unroll
      for (int i = 0; i < 8; ++i) {
        const uint4 w = w8[lane8 * 8 + i];
        const f32x4 ha = hf4[2 * i], hb = hf4[2 * i + 1];
        p += __uint_as_float(w.x << 16) * ha[0] + __uint_as_float(w.x & 0xffff0000u) * ha[1];
        p += __uint_as_float(w.y << 16) * ha[2] + __uint_as_float(w.y & 0xffff0000u) * ha[3];
        p += __uint_as_float(w.z << 16) * hb[0] + __uint_as_float(w.z & 0xffff0000u) * hb[1];
        p += __uint_as_float(w.w << 16) * hb[2] + __uint_as_float(w.w & 0xffff0000u) * hb[3];
      }
      p += __shfl_xor(p, 1); p += __shfl_xor(p, 2); p += __shfl_xor(p, 4);
      return p;
    };

    // ---- q slice: rows j*64 .. +64 of Wq ----
#pragma unroll
    for (int i = 0; i < 2; ++i) {
      const float p = dotw(wq_bf + (size_t)(j * 64 + i * 32 + rowg) * 512);
      if (lane8 == 0) q_s[i * 32 + rowg] = p + bq2[i];
    }
    __syncthreads();

    // ---- partial scores over this slice's 64 h-dims (bf16 kproj) ----
    {
      const uint4* kp = (const uint4*)(kproj_bf + ((size_t)(b * S_ + s_idx)) * H_ + j * 64 + q4 * 16);
      const float4* qp = (const float4*)(q_s + q4 * 16);
      float sc = 0.f;
#pragma unroll
      for (int i = 0; i < 2; ++i) {
        const uint4 k = kp[i];
        const float4 qa = qp[2 * i], qb = qp[2 * i + 1];
        const f32x4 va = wvr[2 * i], vb = wvr[2 * i + 1];
        sc += va[0] * fast_tanh(qa.x + __uint_as_float(k.x << 16));
        sc += va[1] * fast_tanh(qa.y + __uint_as_float(k.x & 0xffff0000u));
        sc += va[2] * fast_tanh(qa.z + __uint_as_float(k.y << 16));
        sc += va[3] * fast_tanh(qa.w + __uint_as_float(k.y & 0xffff0000u));
        sc += vb[0] * fast_tanh(qb.x + __uint_as_float(k.z << 16));
        sc += vb[1] * fast_tanh(qb.y + __uint_as_float(k.z & 0xffff0000u));
        sc += vb[2] * fast_tanh(qb.z + __uint_as_float(k.w << 16));
        sc += vb[3] * fast_tanh(qb.w + __uint_as_float(k.w & 0xffff0000u));
      }
      sc += __shfl_xor(sc, 1); sc += __shfl_xor(sc, 2);
      if (q4 == 0)
        st_agent_f(&partial_st[(((size_t)t * B_ + b) * 8 + j) * 64 + s_idx], sc);
    }
    asm volatile("s_waitcnt vmcnt(0)" ::: "memory");
    __syncthreads();
    if (tid == 0)
      st_agent_i(&st_flags[b * 16 + j], t + 1);

    // ---- gh rows (192), overlaps partial flight ----
#pragma unroll
    for (int i = 0; i < 6; ++i) {
      const int row = (i >> 1) * 512 + j * 64 + (i & 1) * 32 + rowg;
      const float p = dotw(whh_bf + (size_t)row * 512);
      if (lane8 == 0) gh_s[i * 32 + rowg] = p;
    }

    // ---- wait all 8 partials, read once ----
    if (tid < 8) {
      while (ld_agent(&st_flags[b * 16 + tid]) < t + 1) __builtin_amdgcn_s_sleep(1);
    }
    __syncthreads();
    asm volatile("" ::: "memory");
    if (tid < 128) {
      const float4 v = *(const float4*)(partial_st + ((size_t)t * B_ + b) * 512 + tid * 4);
      *(float4*)(ps_s + tid * 4) = v;
    }
    __syncthreads();

    // ---- softmax (redundant per block, bitwise identical) ----
    if (tid < 64) {
      float sc = bv0;
#pragma unroll
      for (int jj = 0; jj < 8; ++jj) sc += ps_s[jj * 64 + tid];
      float m = sc;
#pragma unroll
      for (int d = 32; d > 0; d >>= 1) m = fmaxf(m, __shfl_xor(m, d));
      const float e = __expf(sc - m);
      float sum = e;
#pragma unroll
      for (int d = 32; d > 0; d >>= 1) sum += __shfl_xor(sum, d);
      const float w = e / sum;
      w_s[tid] = w;
      if (j == (b & 7)) attn_out[((size_t)b * T_ + t) * S_ + tid] = w;
    }
    __syncthreads();

    // ---- gic slice j (bf16 encT) ----
    if (tid < 192) {
      const int g = tid >> 6, dd = tid & 63;
      const int grow = g * H_ + j * 64 + dd;
      const uint4* ep = (const uint4*)(encT_bf + (size_t)grow * 2048 + b * 64);
      const float4* wp4 = (const float4*)w_s;
      float a = 0.f;
#pragma unroll
      for (int i = 0; i < 8; ++i) {
        const uint4 e4 = ep[i];
        const float4 w0 = wp4[2 * i], w1 = wp4[2 * i + 1];
        a += __uint_as_float(e4.x << 16) * w0.x + __uint_as_float(e4.x & 0xffff0000u) * w0.y;
        a += __uint_as_float(e4.y << 16) * w0.z + __uint_as_float(e4.y & 0xffff0000u) * w0.w;
        a += __uint_as_float(e4.z << 16) * w1.x + __uint_as_float(e4.z & 0xffff0000u) * w1.y;
        a += __uint_as_float(e4.w << 16) * w1.z + __uint_as_float(e4.w & 0xffff0000u) * w1.w;
      }
      gic_s[tid] = a;
    }
    __syncthreads();

    // ---- gates for h-dims [j*64,(j+1)*64) ----
    if (tid < 64) {
      const int hh = j * 64 + tid;
      const size_t grow = ((size_t)t * B_ + b) * 1536;
      const float ir  = giemb[grow + hh]        + gic_s[tid];
      const float iz  = giemb[grow + 512 + hh]  + gic_s[64 + tid];
      const float in_ = giemb[grow + 1024 + hh] + gic_s[128 + tid];
      const float hr  = gh_s[tid]        + b_hh[hh];
      const float hz  = gh_s[64 + tid]   + b_hh[512 + hh];
      const float hn  = gh_s[128 + tid]  + b_hh[1024 + hh];
      const float rg = fast_sigmoid(ir + hr);
      const float zg = fast_sigmoid(iz + hz);
      const float ng = fast_tanh(in_ + rg * hn);
      const float ho = h_s[j * 68 + tid];
      const float hv = (1.f - zg) * ng + zg * ho;
      st_agent_f(&h_st[(size_t)(t + 1) * (B_ * H_) + b * H_ + hh], hv);
      Hall[((size_t)b * T_ + t) * H_ + hh] = __float2bfloat16(hv);
      if (t == T_ - 1) hfin[b * H_ + hh] = hv;
    }
    asm volatile("s_waitcnt vmcnt(0)" ::: "memory");
    __syncthreads();
    if (tid == 0)
      st_agent_i(&h_flags[b * 16 + j], t + 1);
  }
}

// ---------------- logits GEMM + fused sumexp (XCD-chunked n-tiles) ----------------
// |h|<=1 by GRU construction -> |logit| <~ 10 -> no-max sumexp is fp32-safe.

__global__ __launch_bounds__(256) void k_logits(
    const __hip_bfloat16* __restrict__ Hall, const float* __restrict__ Wo,
    const float* __restrict__ bo, float* __restrict__ out0,
    float* __restrict__ rowsum) {
  __shared__ float pool[128 * 68];
  __hip_bfloat16* Asub = (__hip_bfloat16*)pool;
  __hip_bfloat16* Bsub = (__hip_bfloat16*)(pool + 2048);
  const int tid = threadIdx.x;
  const int lane = tid & 63, wave = tid >> 6;
  const int wr = wave >> 1, wc = wave & 1;
  const int flat = blockIdx.x;                  // 0..3999
  const int nf = (flat & 7) * 500 + (flat >> 3);
  const int m0 = (nf & 15) * 128, n0 = (nf >> 4) * 128;
  f32x4 acc[4][4];
#pragma unroll
  for (int i = 0; i < 4; ++i)
#pragma unroll
    for (int jj = 0; jj < 4; ++jj) acc[i][jj] = (f32x4){0.f, 0.f, 0.f, 0.f};

  for (int k0 = 0; k0 < 512; k0 += 32) {
    uint4 a_v[2];
#pragma unroll
    for (int rr = 0; rr < 2; ++rr) {
      const int seg = tid + rr * 256;
      const int row = seg >> 2, ks8 = (seg & 3) * 8;
      a_v[rr] = *(const uint4*)(Hall + (size_t)(m0 + row) * 512 + k0 + ks8);
    }
    float4 b_v[4];
#pragma unroll
    for (int rr = 0; rr < 4; ++rr) {
      const int idx = tid + rr * 256;
      const int n = idx >> 3, kg = (idx & 7) * 4;
      b_v[rr] = *(const float4*)(Wo + (size_t)(n0 + n) * 512 + k0 + kg);
    }
    __syncthreads();
#pragma unroll
    for (int rr = 0; rr < 2; ++rr) {
      const int seg = tid + rr * 256;
      *(uint4*)(Asub + seg * 8) = a_v[rr];
    }
#pragma unroll
    for (int rr = 0; rr < 4; ++rr) {
      const int idx = tid + rr * 256;
      const int n = idx >> 3, kg = (idx & 7) * 4;
      union { __hip_bfloat16 h[4]; uint2 u; } cv;
      cv.h[0] = __float2bfloat16(b_v[rr].x);
      cv.h[1] = __float2bfloat16(b_v[rr].y);
      cv.h[2] = __float2bfloat16(b_v[rr].z);
      cv.h[3] = __float2bfloat16(b_v[rr].w);
      *(uint2*)(Bsub + n * 32 + kg) = cv.u;
    }
    __syncthreads();
    bf16x8 af[4], bfr[4];
#pragma unroll
    for (int mi = 0; mi < 4; ++mi)
      af[mi] = *(const bf16x8*)(Asub + (wr * 64 + mi * 16 + (lane & 15)) * 32 + (lane >> 4) * 8);
#pragma unroll
    for (int ni = 0; ni < 4; ++ni)
      bfr[ni] = *(const bf16x8*)(Bsub + (wc * 64 + ni * 16 + (lane & 15)) * 32 + (lane >> 4) * 8);
#pragma unroll
    for (int mi = 0; mi < 4; ++mi)
#pragma unroll
      for (int ni = 0; ni < 4; ++ni)
        acc[mi][ni] = __builtin_amdgcn_mfma_f32_16x16x32_bf16(af[mi], bfr[ni], acc[mi][ni], 0, 0, 0);
  }

  float* Cs = pool;
  const int r4 = (lane >> 4) * 4, cc = lane & 15;
#pragma unroll
  for (int hf = 0; hf < 2; ++hf) {
    __syncthreads();
    if (wc == hf) {
#pragma unroll
      for (int ni = 0; ni < 4; ++ni) {
        const float bias = bo[n0 + hf * 64 + ni * 16 + cc];
#pragma unroll
        for (int mi = 0; mi < 4; ++mi)
#pragma unroll
          for (int i = 0; i < 4; ++i)
            Cs[(wr * 64 + mi * 16 + r4 + i) * 68 + ni * 16 + cc] = acc[mi][ni][i] + bias;
      }
    }
    __syncthreads();
    const int rowp = tid >> 4, colg = tid & 15;
#pragma unroll
    for (int pass = 0; pass < 8; ++pass) {
      const int row = pass * 16 + rowp;
      const float4 v = *(const float4*)(Cs + row * 68 + colg * 4);
      *(float4*)(out0 + (size_t)(m0 + row) * V_ + n0 + hf * 64 + colg * 4) = v;
      float e = __expf(v.x) + __expf(v.y) + __expf(v.z) + __expf(v.w);
#pragma unroll
      for (int d = 1; d < 16; d <<= 1) e += __shfl_xor(e, d);
      if (colg == 0) atomicAdd(&rowsum[m0 + row], e);
    }
  }
}

// ---------------- log_softmax apply: out -= log(rowsum[row]) ----------------

__global__ __launch_bounds__(256) void k_lsm_apply(float* __restrict__ out0,
    const float* __restrict__ rowsum) {
  const int row = blockIdx.x, tid = threadIdx.x;
  const float lse = __logf(rowsum[row]);
  float4* p = (float4*)(out0 + (size_t)row * V_);
  for (int i = tid; i < V_ / 4; i += 256) {
    float4 v = p[i];
    v.x -= lse; v.y -= lse; v.z -= lse; v.w -= lse;
    p[i] = v;
  }
}

// ---------------- host ----------------

extern "C" void kernel_launch(void* const* d_in, const int* in_sizes, int n_in,
                              void* d_out, int out_size, void* d_ws, size_t ws_size,
                              hipStream_t stream) {
  (void)in_sizes; (void)n_in; (void)out_size; (void)ws_size;
  const float* enc  = (const float*)d_in[0];
  const float* ehs  = (const float*)d_in[1];
  const int*   tgt  = (const int*)d_in[2];
  const float* emb  = (const float*)d_in[3];
  const float* Wq   = (const float*)d_in[4];
  const float* bq   = (const float*)d_in[5];
  const float* Wk   = (const float*)d_in[6];
  const float* bk   = (const float*)d_in[7];
  const float* Wv   = (const float*)d_in[8];
  const float* bv   = (const float*)d_in[9];
  const float* W_ih = (const float*)d_in[10];
  const float* W_hh = (const float*)d_in[11];
  const float* b_ih = (const float*)d_in[12];
  const float* b_hh = (const float*)d_in[13];
  const float* Wo   = (const float*)d_in[14];
  const float* bo   = (const float*)d_in[15];

  float* out0 = (float*)d_out;                          // log_probs [2048, V]
  float* out1 = out0 + (size_t)B_ * T_ * V_;            // h_final [B*H]
  float* out2 = out1 + (size_t)B_ * H_;                 // attentions [B*T, S]

  // out0 doubles as scratch; k_logits overwrites all of it afterwards.
  float* kproj    = out0;                 // [0, 1,048,576)
  float* giemb    = out0 + 1048576;       // [.., 4,194,304)
  float* encprojT = out0 + 4194304;       // [1536][2048] -> [.., 7,340,032)
  float* h_st     = out0 + 7340032;       // 65 x 16384 -> [.., 8,404,992)
  float* partial  = out0 + 8404992;       // 64x32x512 -> [.., 9,453,568)
  __hip_bfloat16* enc_bf   = (__hip_bfloat16*)(out0 + 9453568);   // 1M bf16
  __hip_bfloat16* emb_bf   = (__hip_bfloat16*)(out0 + 9977856);   // 1M bf16
  __hip_bfloat16* wihc_bf  = (__hip_bfloat16*)(out0 + 10502144);  // 0.75M bf16
  __hip_bfloat16* wq_bf    = (__hip_bfloat16*)(out0 + 10895360);  // 256K bf16
  __hip_bfloat16* whh_bf   = (__hip_bfloat16*)(out0 + 11026432);  // 0.75M bf16
  __hip_bfloat16* kproj_bf = (__hip_bfloat16*)(out0 + 11419648);  // 1M bf16
  __hip_bfloat16* encT_bf  = (__hip_bfloat16*)(out0 + 11943936);  // 3M bf16

  __hip_bfloat16* Hall = (__hip_bfloat16*)d_ws;                    // 2 MB
  int* flags = (int*)((char*)d_ws + (size_t)2 * 1024 * 1024);      // 1024 ints
  float* rowsum = (float*)((char*)d_ws + (size_t)2 * 1024 * 1024 + 4096);  // 2048 f

  k_emb_gather<<<2048, 256, 0, stream>>>(tgt, emb, emb_bf);
  k_cvt_dense<<<1024, 256, 0, stream>>>(enc, enc_bf, 262144);
  k_cvt_wihc<<<1536, 128, 0, stream>>>(W_ih, wihc_bf);
  k_cvt_wqh<<<2048, 256, 0, stream>>>(Wq, W_hh, wq_bf, whh_bf);
  k_init<<<64, 256, 0, stream>>>(ehs, h_st, flags, rowsum);

  // kproj[2048,512] = enc @ Wk^T + bk
  k_gemm_bf16<<<dim3(4, 16), 256, 0, stream>>>(enc_bf, 512, Wk, 512, bk, kproj, 512, 512);
  // giemb[2048,1536] = emb_all @ W_ih[:, :512]^T + b_ih
  k_gemm_bf16<<<dim3(12, 16), 256, 0, stream>>>(emb_bf, 512, W_ih, 1024, b_ih, giemb, 1536, 512);
  // encprojT[1536,2048] = W_ihc @ enc^T
  k_gemm_bf16<<<dim3(16, 12), 256, 0, stream>>>(wihc_bf, 512, enc, 512, nullptr, encprojT, 2048, 512);

  // bf16 copies for the recurrence's streamed operands
  k_cvt_dense<<<1024, 256, 0, stream>>>(kproj, kproj_bf, 262144);
  k_cvt_dense<<<3072, 256, 0, stream>>>(encprojT, encT_bf, 786432);

  k_recur<<<256, 256, 0, stream>>>(wq_bf, whh_bf, bq, kproj_bf, Wv, bv, encT_bf,
                                   giemb, b_hh, h_st, partial, flags,
                                   out2, Hall, out1);

  k_logits<<<4000, 256, 0, stream>>>(Hall, Wo, bo, out0, rowsum);
  k_lsm_apply<<<(B_ * T_), 256, 0, stream>>>(out0, rowsum);
}